// Round 1
// baseline (4739.914 us; speedup 1.0000x reference)
//
#include <hip/hip_runtime.h>

// Problem constants (fixed by the reference)
#define DD        512        // D_IN == D_HID
#define DOUT      256
#define N1DST     45056
#define N2DST     4096
#define E1N       450560
#define E2N       40960

// ---------------------------------------------------------------------------
// Scatter-add: msg[dst] += src[esrc], deg[dst] += 1.  One thread per float4
// of one edge's feature row (D/4 = 128 float4 per edge).
// ---------------------------------------------------------------------------
__global__ __launch_bounds__(256)
void scatter_add_kernel(const float* __restrict__ src,
                        const int* __restrict__ esrc,
                        const int* __restrict__ edst,
                        float* __restrict__ msg,
                        float* __restrict__ deg,
                        int E) {
    long long tid = (long long)blockIdx.x * blockDim.x + threadIdx.x;
    long long total = (long long)E * (DD / 4);
    if (tid >= total) return;
    int e = (int)(tid >> 7);      // / 128
    int t = (int)(tid & 127);
    int s = esrc[e];
    int d = edst[e];
    float4 v = ((const float4*)(src + (size_t)s * DD))[t];
    float* drow = msg + (size_t)d * DD + t * 4;
    unsafeAtomicAdd(drow + 0, v.x);
    unsafeAtomicAdd(drow + 1, v.y);
    unsafeAtomicAdd(drow + 2, v.z);
    unsafeAtomicAdd(drow + 3, v.w);
    if (t == 0) unsafeAtomicAdd(deg + d, 1.0f);
}

// ---------------------------------------------------------------------------
// agg = (msg + h_dst) / (deg + 1), in place in msg. One thread per float4.
// ---------------------------------------------------------------------------
__global__ __launch_bounds__(256)
void agg_finish_kernel(float* __restrict__ msg,
                       const float* __restrict__ hdst,
                       const float* __restrict__ deg,
                       int total4) {
    int i = blockIdx.x * blockDim.x + threadIdx.x;
    if (i >= total4) return;
    int row = i >> 7;             // / (DD/4)
    float scale = 1.0f / (deg[row] + 1.0f);
    float4 m = ((float4*)msg)[i];
    float4 h = ((const float4*)hdst)[i];
    m.x = (m.x + h.x) * scale;
    m.y = (m.y + h.y) * scale;
    m.z = (m.z + h.z) * scale;
    m.w = (m.w + h.w) * scale;
    ((float4*)msg)[i] = m;
}

// ---------------------------------------------------------------------------
// fp32 tiled GEMM: C[M,N] = A[M,K] @ B[K,N] + bias[N], optional ReLU.
// 64x64 tile, BK=16, 256 threads, 4x4 micro-tile per thread.
// M % 64 == 0, N % 64 == 0, K % 16 == 0 (holds for all our shapes).
// ---------------------------------------------------------------------------
template <bool RELU>
__global__ __launch_bounds__(256)
void gemm_bias_kernel(const float* __restrict__ A,
                      const float* __restrict__ B,
                      const float* __restrict__ bias,
                      float* __restrict__ C,
                      int M, int N, int K) {
    __shared__ float sA[16][64];   // [k][m]
    __shared__ float sB[16][64];   // [k][n]

    int tid = threadIdx.x;
    int tx = tid & 15;             // 0..15  -> n
    int ty = tid >> 4;             // 0..15  -> m
    int m0 = blockIdx.y * 64;
    int n0 = blockIdx.x * 64;

    // A staging: thread loads float4 at row (tid&63), k-quad (tid>>6)
    int arow = tid & 63;
    int akq  = tid >> 6;           // 0..3
    const float* Ap = A + (size_t)(m0 + arow) * K + akq * 4;
    // B staging: thread loads float4 at k-row (tid>>4), col (tid&15)*4
    int bk = tid >> 4;             // 0..15
    int bc = (tid & 15) * 4;
    const float* Bp = B + (size_t)bk * N + n0 + bc;

    float acc[4][4] = {};

    for (int k0 = 0; k0 < K; k0 += 16) {
        float4 av = *(const float4*)(Ap + k0);
        float4 bv = *(const float4*)(Bp + (size_t)k0 * N);
        sA[akq * 4 + 0][arow] = av.x;
        sA[akq * 4 + 1][arow] = av.y;
        sA[akq * 4 + 2][arow] = av.z;
        sA[akq * 4 + 3][arow] = av.w;
        *(float4*)&sB[bk][bc] = bv;
        __syncthreads();
#pragma unroll
        for (int kk = 0; kk < 16; ++kk) {
            float4 a = *(const float4*)&sA[kk][ty * 4];
            float4 b = *(const float4*)&sB[kk][tx * 4];
            acc[0][0] += a.x * b.x; acc[0][1] += a.x * b.y; acc[0][2] += a.x * b.z; acc[0][3] += a.x * b.w;
            acc[1][0] += a.y * b.x; acc[1][1] += a.y * b.y; acc[1][2] += a.y * b.z; acc[1][3] += a.y * b.w;
            acc[2][0] += a.z * b.x; acc[2][1] += a.z * b.y; acc[2][2] += a.z * b.z; acc[2][3] += a.z * b.w;
            acc[3][0] += a.w * b.x; acc[3][1] += a.w * b.y; acc[3][2] += a.w * b.z; acc[3][3] += a.w * b.w;
        }
        __syncthreads();
    }

    float bvs[4];
#pragma unroll
    for (int j = 0; j < 4; ++j) bvs[j] = bias[n0 + tx * 4 + j];

#pragma unroll
    for (int i = 0; i < 4; ++i) {
        size_t m = (size_t)(m0 + ty * 4 + i);
        float4 o;
        o.x = acc[i][0] + bvs[0];
        o.y = acc[i][1] + bvs[1];
        o.z = acc[i][2] + bvs[2];
        o.w = acc[i][3] + bvs[3];
        if (RELU) {
            o.x = fmaxf(o.x, 0.0f);
            o.y = fmaxf(o.y, 0.0f);
            o.z = fmaxf(o.z, 0.0f);
            o.w = fmaxf(o.w, 0.0f);
        }
        *(float4*)(C + m * N + n0 + tx * 4) = o;
    }
}

// ---------------------------------------------------------------------------
extern "C" void kernel_launch(void* const* d_in, const int* in_sizes, int n_in,
                              void* d_out, int out_size, void* d_ws, size_t ws_size,
                              hipStream_t stream) {
    const float* feats = (const float*)d_in[0];   // (495616, 512)
    const float* W1    = (const float*)d_in[1];   // (512, 512)
    const float* b1    = (const float*)d_in[2];   // (512,)
    const float* W2    = (const float*)d_in[3];   // (512, 256)
    const float* b2    = (const float*)d_in[4];   // (256,)
    const int* es1     = (const int*)d_in[5];     // (E1,)
    const int* ed1     = (const int*)d_in[6];
    const int* es2     = (const int*)d_in[7];
    const int* ed2     = (const int*)d_in[8];
    float* out         = (float*)d_out;           // (4096, 256)

    // Workspace layout (floats):
    //   msg1 (also reused as msg2) : [0, 23068672)
    //   deg1                       : [23068672, 23113728)
    //   deg2                       : [23113728, 23117824)
    //   h                          : [23117824, 46186496)
    float* ws    = (float*)d_ws;
    float* msg1  = ws;
    float* deg1  = ws + (size_t)N1DST * DD;
    float* deg2  = deg1 + N1DST;
    float* h     = deg2 + N2DST;
    float* msg2  = ws;                  // reuse msg1's space after GEMM1

    // 1) zero msg1 + deg1 + deg2
    size_t zero1_bytes = ((size_t)N1DST * DD + N1DST + N2DST) * sizeof(float);
    hipMemsetAsync(d_ws, 0, zero1_bytes, stream);

    // 2) layer-1 scatter
    {
        long long total = (long long)E1N * (DD / 4);
        int blocks = (int)((total + 255) / 256);
        scatter_add_kernel<<<blocks, 256, 0, stream>>>(feats, es1, ed1, msg1, deg1, E1N);
    }
    // 3) agg1 = (msg1 + feats[:N1DST]) / (deg1 + 1)
    {
        int total4 = N1DST * DD / 4;
        agg_finish_kernel<<<(total4 + 255) / 256, 256, 0, stream>>>(msg1, feats, deg1, total4);
    }
    // 4) h = relu(agg1 @ W1 + b1)
    {
        dim3 grid(DD / 64, N1DST / 64);
        gemm_bias_kernel<true><<<grid, 256, 0, stream>>>(msg1, W1, b1, h, N1DST, DD, DD);
    }
    // 5) zero msg2 region (deg2 still zero-initialized and untouched)
    hipMemsetAsync(msg2, 0, (size_t)N2DST * DD * sizeof(float), stream);

    // 6) layer-2 scatter
    {
        long long total = (long long)E2N * (DD / 4);
        int blocks = (int)((total + 255) / 256);
        scatter_add_kernel<<<blocks, 256, 0, stream>>>(h, es2, ed2, msg2, deg2, E2N);
    }
    // 7) agg2 = (msg2 + h[:N2DST]) / (deg2 + 1)
    {
        int total4 = N2DST * DD / 4;
        agg_finish_kernel<<<(total4 + 255) / 256, 256, 0, stream>>>(msg2, h, deg2, total4);
    }
    // 8) out = agg2 @ W2 + b2
    {
        dim3 grid(DOUT / 64, N2DST / 64);
        gemm_bias_kernel<false><<<grid, 256, 0, stream>>>(msg2, W2, b2, out, N2DST, DOUT, DD);
    }
}